// Round 1
// baseline (41553.079 us; speedup 1.0000x reference)
//
#include <hip/hip_runtime.h>
#include <hip/hip_fp16.h>

#define BB   32
#define TENC 256
#define EE   512
#define TDEC 200
#define NM   80
#define HH   1024
#define AA   128
#define GG   4096   // 4*HH

__device__ __forceinline__ float sigf(float x){ return 1.0f/(1.0f + __expf(-x)); }
__device__ __forceinline__ float tanhfast(float x){ return 1.0f - 2.0f/(1.0f + __expf(2.0f*x)); }

// ---------------- precompute kernels ----------------

__global__ void k_zero(float* __restrict__ p, int n){
    int i = blockIdx.x*blockDim.x + threadIdx.x;
    if(i < n) p[i] = 0.f;
}

__global__ void k_cvt_half(const float* __restrict__ src, __half* __restrict__ dst, int n){
    int i = blockIdx.x*blockDim.x + threadIdx.x;
    int stride = gridDim.x*blockDim.x;
    for(; i<n; i+=stride) dst[i] = __float2half(src[i]);
}

// proc_enc[b,t,:] = inputs[b,t,:] @ W_enc  -> fp16.  One block per (b,t) row.
__global__ __launch_bounds__(128) void k_proc_enc(const float* __restrict__ inputs,
                                                  const float* __restrict__ Wenc,
                                                  __half* __restrict__ pe_h){
    const int row = blockIdx.x;          // b*TENC + t
    const int a   = threadIdx.x;         // 0..127
    const float* in = inputs + (size_t)row*EE;
    float acc = 0.f;
    for(int k=0;k<EE;k++) acc = fmaf(in[k], Wenc[k*AA + a], acc);
    pe_h[(size_t)row*AA + a] = __float2half(acc);
}

// prenet for all t: xT[t][k][b] (transposed for the LSTM GEMM). One block per t.
__global__ __launch_bounds__(256) void k_prenet(const float* __restrict__ pmels,
                                                const float* __restrict__ pw1, const float* __restrict__ pb1,
                                                const float* __restrict__ pw2, const float* __restrict__ pb2,
                                                float* __restrict__ xT){
    const int t = blockIdx.x;
    __shared__ float pm[BB*NM];       // 2560 f
    __shared__ float h1s[BB*256];     // 32 KB
    const int tid = threadIdx.x;
    for(int el=tid; el<BB*NM; el+=256){
        const int b = el/NM, m = el%NM;
        pm[el] = (t==0) ? 0.f : pmels[(size_t)(b*NM + m)*TDEC + (t-1)];
    }
    __syncthreads();
    const int a = tid;                // 0..255
    float acc[BB];
    #pragma unroll
    for(int b=0;b<BB;b++) acc[b]=0.f;
    for(int m=0;m<NM;m++){
        const float w = pw1[m*256 + a];
        #pragma unroll
        for(int b=0;b<BB;b++) acc[b] = fmaf(pm[b*NM+m], w, acc[b]);
    }
    {
        const float bias = pb1[a];
        for(int b=0;b<BB;b++) h1s[b*256+a] = fmaxf(acc[b]+bias, 0.f);
    }
    __syncthreads();
    #pragma unroll
    for(int b=0;b<BB;b++) acc[b]=0.f;
    for(int k=0;k<256;k++){
        const float w = pw2[k*256 + a];
        #pragma unroll
        for(int b=0;b<BB;b++) acc[b] = fmaf(h1s[b*256+k], w, acc[b]);
    }
    {
        const float bias = pb2[a];
        float* dst = xT + ((size_t)t*256 + a)*BB;
        #pragma unroll
        for(int b=0;b<BB;b++) dst[b] = fmaxf(acc[b]+bias, 0.f);
    }
}

// Mloc[d][a] = sum_ch conv_w[ch,d]*W_loc[ch,a]; cbp[a] = sum_ch conv_b[ch]*W_loc[ch,a]
__global__ void k_mloc(const float* __restrict__ conv_w, const float* __restrict__ conv_b,
                       const float* __restrict__ W_loc, float* __restrict__ Mloc, float* __restrict__ cbp){
    const int a = threadIdx.x;   // 128
    for(int d=0; d<31; d++){
        float s = 0.f;
        for(int ch=0; ch<32; ch++) s = fmaf(conv_w[ch*31 + d], W_loc[ch*AA + a], s);
        Mloc[d*AA + a] = s;
    }
    float s = 0.f;
    for(int ch=0; ch<32; ch++) s = fmaf(conv_b[ch], W_loc[ch*AA + a], s);
    cbp[a] = s;
}

// ---------------- per-step kernels ----------------

// Fused gate-GEMM + LSTM cell. Inputs transposed [k][b]. Up to 3 K-segments.
// Block covers 4 gates x 4 cells (16 weight columns); thread=(col 16, kp 16), acc[32 batch].
__global__ __launch_bounds__(256) void k_lstm(
    const float* __restrict__ in0, const float* __restrict__ w0, int len0,
    const float* __restrict__ in1, const float* __restrict__ w1, int len1,
    const float* __restrict__ in2, const float* __restrict__ w2, int len2,
    int chunk, const float* __restrict__ bias,
    float* __restrict__ cst, float* __restrict__ hT)
{
    __shared__ float part[16*16*36];   // [kp][col][b], stride 36 to break bank conflicts
    const int tid  = threadIdx.x;
    const int col  = tid & 15;
    const int kp   = tid >> 4;
    const int gate = col >> 2;
    const int cell = blockIdx.x*4 + (col & 3);
    const int wcol = gate*HH + cell;

    float acc[32];
    #pragma unroll
    for(int j=0;j<32;j++) acc[j]=0.f;

    const int k0 = kp*chunk, k1 = k0 + chunk;
    const float* ins[3]  = {in0,in1,in2};
    const float* wss[3]  = {w0,w1,w2};
    const int    lens[3] = {len0,len1,len2};
    int base = 0;
    for(int s=0;s<3;s++){
        const int hiB = base + lens[s];
        const int lo  = (k0 > base) ? k0 : base;
        const int hi  = (k1 < hiB) ? k1 : hiB;
        const float* inp = ins[s];
        const float* wp  = wss[s];
        for(int k=lo; k<hi; k++){
            const int r = k - base;
            const float w = wp[(size_t)r*GG + wcol];
            const float4* iv = (const float4*)(inp + (size_t)r*BB);
            #pragma unroll
            for(int j=0;j<8;j++){
                const float4 v = iv[j];
                acc[4*j+0] = fmaf(w, v.x, acc[4*j+0]);
                acc[4*j+1] = fmaf(w, v.y, acc[4*j+1]);
                acc[4*j+2] = fmaf(w, v.z, acc[4*j+2]);
                acc[4*j+3] = fmaf(w, v.w, acc[4*j+3]);
            }
        }
        base = hiB;
    }
    {
        float* pdst = part + (kp*16+col)*36;
        #pragma unroll
        for(int j=0;j<8;j++)
            ((float4*)pdst)[j] = make_float4(acc[4*j],acc[4*j+1],acc[4*j+2],acc[4*j+3]);
    }
    __syncthreads();
    if(tid < 128){
        const int b   = tid & 31;
        const int cl  = tid >> 5;
        const int c2g = blockIdx.x*4 + cl;
        float gs[4];
        #pragma unroll
        for(int g=0; g<4; g++){
            const int c2 = g*4 + cl;
            float s = bias[g*HH + c2g];
            #pragma unroll
            for(int kq=0; kq<16; kq++) s += part[(kq*16+c2)*36 + b];
            gs[g] = s;
        }
        const float ig = sigf(gs[0]);
        const float fg = sigf(gs[1]);
        const float gv = tanhfast(gs[2]);
        const float og = sigf(gs[3]);
        const int idx = c2g*BB + b;
        const float cn = fg*cst[idx] + ig*gv;
        cst[idx] = cn;
        hT[idx]  = og*tanhfast(cn);
    }
}

// q = h2 @ W_q (blocks 0..7), out_h2 = h2 @ Wp[0:1024] (blocks 8..11)
__global__ __launch_bounds__(256) void k_q_outh2(
    const float* __restrict__ h2T, const float* __restrict__ Wq,
    const float* __restrict__ Wp, float* __restrict__ q_ws, float* __restrict__ outh2)
{
    __shared__ float part[16*16*36];
    const int tid = threadIdx.x;
    if(blockIdx.x < 8){
        const int al = tid & 15, kp = tid >> 4;
        const int a  = blockIdx.x*16 + al;
        float acc[32];
        #pragma unroll
        for(int j=0;j<32;j++) acc[j]=0.f;
        const int k0 = kp*64, k1 = k0+64;
        for(int k=k0;k<k1;k++){
            const float w = Wq[k*AA + a];
            const float4* iv = (const float4*)(h2T + (size_t)k*BB);
            #pragma unroll
            for(int j=0;j<8;j++){
                const float4 v = iv[j];
                acc[4*j+0] = fmaf(w, v.x, acc[4*j+0]);
                acc[4*j+1] = fmaf(w, v.y, acc[4*j+1]);
                acc[4*j+2] = fmaf(w, v.z, acc[4*j+2]);
                acc[4*j+3] = fmaf(w, v.w, acc[4*j+3]);
            }
        }
        {
            float* pdst = part + (kp*16+al)*36;
            #pragma unroll
            for(int j=0;j<8;j++)
                ((float4*)pdst)[j] = make_float4(acc[4*j],acc[4*j+1],acc[4*j+2],acc[4*j+3]);
        }
        __syncthreads();
        for(int it=tid; it<512; it+=256){
            const int a2 = it >> 5, b = it & 31;
            float s = 0.f;
            #pragma unroll
            for(int kq=0;kq<16;kq++) s += part[(kq*16+a2)*36 + b];
            q_ws[b*AA + blockIdx.x*16 + a2] = s;
        }
    } else {
        const int mg = blockIdx.x - 8;
        const int ml = tid % 20, kp = tid / 20;   // kp 0..12; kp==12 idle
        if(kp < 12){
            const int m  = mg*20 + ml;
            float acc[32];
            #pragma unroll
            for(int j=0;j<32;j++) acc[j]=0.f;
            const int k0 = kp*86;
            const int k1 = (k0+86 < 1024) ? (k0+86) : 1024;
            for(int k=k0;k<k1;k++){
                const float w = Wp[k*80 + m];
                const float4* iv = (const float4*)(h2T + (size_t)k*BB);
                #pragma unroll
                for(int j=0;j<8;j++){
                    const float4 v = iv[j];
                    acc[4*j+0] = fmaf(w, v.x, acc[4*j+0]);
                    acc[4*j+1] = fmaf(w, v.y, acc[4*j+1]);
                    acc[4*j+2] = fmaf(w, v.z, acc[4*j+2]);
                    acc[4*j+3] = fmaf(w, v.w, acc[4*j+3]);
                }
            }
            float* pdst = part + (kp*20+ml)*36;
            #pragma unroll
            for(int j=0;j<8;j++)
                ((float4*)pdst)[j] = make_float4(acc[4*j],acc[4*j+1],acc[4*j+2],acc[4*j+3]);
        }
        __syncthreads();
        for(int it=tid; it<640; it+=256){
            const int m2 = it % 20, b = it / 20;
            float s = 0.f;
            #pragma unroll
            for(int kq=0;kq<12;kq++) s += part[(kq*20+m2)*36 + b];
            outh2[b*80 + mg*20 + m2] = s;
        }
    }
}

// energies[b,t] = sum_a tanh(q[a]+cbp[a]+pe[b,t,a]+conv) * v_e[a]
// grid: 128 blocks = (b in 0..31) x (quarter in 0..3, 64 t each). wave w covers a-range w*32..+32.
__global__ __launch_bounds__(256) void k_energy(
    const float* __restrict__ q_ws, const float* __restrict__ cbp,
    const float* __restrict__ MlocG, const float* __restrict__ v_e,
    const float* __restrict__ awc, const __half* __restrict__ pe_h,
    float* __restrict__ e_ws)
{
    const int b = blockIdx.x & 31, quarter = blockIdx.x >> 5;
    const int t0 = quarter*64;
    __shared__ float qc[AA], ml[31*AA], ve[AA], awin[94], epart[256];
    const int tid = threadIdx.x;
    if(tid < AA){ qc[tid] = q_ws[b*AA+tid] + cbp[tid]; ve[tid] = v_e[tid]; }
    for(int i=tid; i<31*AA; i+=256) ml[i] = MlocG[i];
    if(tid < 94){
        const int g = t0 - 15 + tid;
        awin[tid] = (g>=0 && g<TENC) ? awc[b*TENC+g] : 0.f;
    }
    __syncthreads();
    const int tl = tid & 63, aq = tid >> 6;
    const int t  = t0 + tl;
    float awr[31];
    #pragma unroll
    for(int d=0;d<31;d++) awr[d] = awin[tl+d];
    float s[32];
    const __half* pe = pe_h + ((size_t)(b*TENC+t))*AA + aq*32;
    #pragma unroll
    for(int j=0;j<32;j++) s[j] = qc[aq*32+j] + __half2float(pe[j]);
    for(int d=0;d<31;d++){
        const float w = awr[d];
        const float4* m4 = (const float4*)&ml[d*AA + aq*32];
        #pragma unroll
        for(int jj=0;jj<8;jj++){
            const float4 v = m4[jj];
            s[4*jj+0] = fmaf(w, v.x, s[4*jj+0]);
            s[4*jj+1] = fmaf(w, v.y, s[4*jj+1]);
            s[4*jj+2] = fmaf(w, v.z, s[4*jj+2]);
            s[4*jj+3] = fmaf(w, v.w, s[4*jj+3]);
        }
    }
    float esum = 0.f;
    #pragma unroll
    for(int j=0;j<32;j++) esum = fmaf(tanhfast(s[j]), ve[aq*32+j], esum);
    epart[aq*64 + tl] = esum;
    __syncthreads();
    if(tid < 64){
        const float e2 = epart[tid] + epart[64+tid] + epart[128+tid] + epart[192+tid];
        e_ws[b*TENC + t0 + tid] = e2;
    }
}

// softmax + ctx + aw_cum update + output projection (ctx part). One block per b.
__global__ __launch_bounds__(256) void k_attn_out(
    const float* __restrict__ e_ws, const __half* __restrict__ inputs_h,
    float* __restrict__ awc, float* __restrict__ ctxT,
    const float* __restrict__ outh2_ws, const float* __restrict__ Wp_c,
    const float* __restrict__ bp, float* __restrict__ dout, int t)
{
    const int b = blockIdx.x, tid = threadIdx.x;
    __shared__ float aw[TENC], ctxs[EE], red[256], sred[8];
    const float e = e_ws[b*TENC + tid];
    float m = e;
    #pragma unroll
    for(int o=32;o>=1;o>>=1) m = fmaxf(m, __shfl_xor(m, o));
    if((tid&63)==0) sred[tid>>6] = m;
    __syncthreads();
    m = fmaxf(fmaxf(sred[0],sred[1]), fmaxf(sred[2],sred[3]));
    const float p = __expf(e - m);
    float sum = p;
    #pragma unroll
    for(int o=32;o>=1;o>>=1) sum += __shfl_xor(sum, o);
    if((tid&63)==0) sred[4+(tid>>6)] = sum;
    __syncthreads();
    sum = sred[4]+sred[5]+sred[6]+sred[7];
    const float awv = p/sum;
    aw[tid] = awv;
    awc[b*TENC + tid] += awv;
    __syncthreads();

    float a0=0.f, a1=0.f;
    const __half* ib = inputs_h + (size_t)b*TENC*EE;
    for(int tt=0; tt<TENC; tt+=4){
        const float4 w4 = *(const float4*)&aw[tt];
        a0 = fmaf(w4.x, __half2float(ib[(size_t)(tt+0)*EE + tid]),       a0);
        a1 = fmaf(w4.x, __half2float(ib[(size_t)(tt+0)*EE + 256 + tid]), a1);
        a0 = fmaf(w4.y, __half2float(ib[(size_t)(tt+1)*EE + tid]),       a0);
        a1 = fmaf(w4.y, __half2float(ib[(size_t)(tt+1)*EE + 256 + tid]), a1);
        a0 = fmaf(w4.z, __half2float(ib[(size_t)(tt+2)*EE + tid]),       a0);
        a1 = fmaf(w4.z, __half2float(ib[(size_t)(tt+2)*EE + 256 + tid]), a1);
        a0 = fmaf(w4.w, __half2float(ib[(size_t)(tt+3)*EE + tid]),       a0);
        a1 = fmaf(w4.w, __half2float(ib[(size_t)(tt+3)*EE + 256 + tid]), a1);
    }
    ctxT[(size_t)tid*BB + b]       = a0;
    ctxT[(size_t)(tid+256)*BB + b] = a1;
    ctxs[tid] = a0; ctxs[tid+256] = a1;
    __syncthreads();

    const int m2 = tid & 127, kh = tid >> 7;
    float s2 = 0.f;
    if(m2 < NM){
        const float* wp = Wp_c + (size_t)kh*256*NM + m2;
        for(int j=0;j<256;j+=4){
            const float4 c4 = *(const float4*)&ctxs[kh*256+j];
            s2 = fmaf(c4.x, wp[(size_t)(j+0)*NM], s2);
            s2 = fmaf(c4.y, wp[(size_t)(j+1)*NM], s2);
            s2 = fmaf(c4.z, wp[(size_t)(j+2)*NM], s2);
            s2 = fmaf(c4.w, wp[(size_t)(j+3)*NM], s2);
        }
    }
    red[tid] = s2;
    __syncthreads();
    if(tid < NM){
        const float o = red[tid] + red[128+tid] + outh2_ws[b*NM+tid] + bp[tid];
        dout[((size_t)t*BB + b)*NM + tid] = o;
    }
}

// ---------------- host ----------------

extern "C" void kernel_launch(void* const* d_in, const int* in_sizes, int n_in,
                              void* d_out, int out_size, void* d_ws, size_t ws_size,
                              hipStream_t stream)
{
    const float* inputs = (const float*)d_in[0];
    const float* pmels  = (const float*)d_in[1];
    const float* W_enc  = (const float*)d_in[2];
    const float* W_q    = (const float*)d_in[3];
    const float* conv_w = (const float*)d_in[4];
    const float* conv_b = (const float*)d_in[5];
    const float* W_loc  = (const float*)d_in[6];
    const float* v_e    = (const float*)d_in[7];
    const float* pw1    = (const float*)d_in[8];
    const float* pb1    = (const float*)d_in[9];
    const float* pw2    = (const float*)d_in[10];
    const float* pb2    = (const float*)d_in[11];
    const float* Wi1    = (const float*)d_in[12];
    const float* Wh1    = (const float*)d_in[13];
    const float* bl1    = (const float*)d_in[14];
    const float* Wi2    = (const float*)d_in[15];
    const float* Wh2    = (const float*)d_in[16];
    const float* bl2    = (const float*)d_in[17];
    const float* Wp     = (const float*)d_in[18];
    const float* bp     = (const float*)d_in[19];
    float* out = (float*)d_out;
    (void)in_sizes; (void)n_in; (void)out_size; (void)ws_size;

    char* ws = (char*)d_ws;
    size_t off = 0;
    auto carve = [&](size_t bytes)->char* {
        char* p = ws + off;
        off += (bytes + 255) & ~(size_t)255;
        return p;
    };
    __half* inputs_h = (__half*)carve((size_t)BB*TENC*EE*2);
    __half* pe_h     = (__half*)carve((size_t)BB*TENC*AA*2);
    float*  xT       = (float*) carve((size_t)TDEC*256*BB*4);
    // state block (zeroed each launch): ctxT | h1a | h1b | h2a | h2b | c1 | c2 | awc
    const int NSTATE = 16384 + 4*32768 + 2*32768 + 8192;  // 221184 floats
    float* states = (float*)carve((size_t)NSTATE*4);
    float* ctxT = states;
    float* h1a  = states + 16384;
    float* h1b  = states + 49152;
    float* h2a  = states + 81920;
    float* h2b  = states + 114688;
    float* c1   = states + 147456;
    float* c2   = states + 180224;
    float* awc  = states + 212992;
    float* q_ws   = (float*)carve((size_t)BB*AA*4);
    float* outh2  = (float*)carve((size_t)BB*NM*4);
    float* e_ws   = (float*)carve((size_t)BB*TENC*4);
    float* Mloc   = (float*)carve((size_t)31*AA*4);
    float* cbp    = (float*)carve((size_t)AA*4);

    // one-time (per launch) precompute
    k_cvt_half<<<2048,256,0,stream>>>(inputs, inputs_h, BB*TENC*EE);
    k_proc_enc<<<BB*TENC,128,0,stream>>>(inputs, W_enc, pe_h);
    k_prenet<<<TDEC,256,0,stream>>>(pmels, pw1,pb1,pw2,pb2, xT);
    k_mloc<<<1,128,0,stream>>>(conv_w, conv_b, W_loc, Mloc, cbp);
    k_zero<<<(NSTATE+255)/256,256,0,stream>>>(states, NSTATE);

    for(int t=0; t<TDEC; t++){
        float* h1wr = (t&1) ? h1b : h1a;
        float* h1rd = (t&1) ? h1a : h1b;
        float* h2wr = (t&1) ? h2b : h2a;
        float* h2rd = (t&1) ? h2a : h2b;

        // LSTM1: gates = x_t@Wi1[0:256] + ctx@Wi1[256:768] + h1@Wh1 + bl1
        k_lstm<<<256,256,0,stream>>>(xT + (size_t)t*256*BB, Wi1, 256,
                                     ctxT, Wi1 + (size_t)256*GG, 512,
                                     h1rd, Wh1, 1024,
                                     112, bl1, c1, h1wr);
        // LSTM2: gates = h1@Wi2 + h2@Wh2 + bl2
        k_lstm<<<256,256,0,stream>>>(h1wr, Wi2, 1024,
                                     h2rd, Wh2, 1024,
                                     (const float*)nullptr, (const float*)nullptr, 0,
                                     128, bl2, c2, h2wr);
        k_q_outh2<<<12,256,0,stream>>>(h2wr, W_q, Wp, q_ws, outh2);
        k_energy<<<128,256,0,stream>>>(q_ws, cbp, Mloc, v_e, awc, pe_h, e_ws);
        k_attn_out<<<BB,256,0,stream>>>(e_ws, inputs_h, awc, ctxT, outh2,
                                        Wp + (size_t)1024*NM, bp, out, t);
    }
}

// Round 2
// 23249.902 us; speedup vs baseline: 1.7872x; 1.7872x over previous
//
#include <hip/hip_runtime.h>
#include <hip/hip_fp16.h>

#define BB   32
#define TENC 256
#define EE   512
#define TDEC 200
#define NM   80
#define HH   1024
#define AA   128
#define GG   4096   // 4*HH

typedef _Float16 h8 __attribute__((ext_vector_type(8)));

__device__ __forceinline__ float sigf(float x){ return 1.0f/(1.0f + __expf(-x)); }
__device__ __forceinline__ float tanhfast(float x){ return 1.0f - 2.0f/(1.0f + __expf(2.0f*x)); }

// ---------------- precompute kernels ----------------

__global__ void k_zero(float* __restrict__ p, int n){
    int i = blockIdx.x*blockDim.x + threadIdx.x;
    if(i < n) p[i] = 0.f;
}

__global__ void k_cvt_half(const float* __restrict__ src, __half* __restrict__ dst, int n){
    int i = blockIdx.x*blockDim.x + threadIdx.x;
    int stride = gridDim.x*blockDim.x;
    for(; i<n; i+=stride) dst[i] = __float2half(src[i]);
}

// transpose fp32 src[k][c] (row stride C) -> fp16 dst[c][k] (row stride dstStride)
__global__ __launch_bounds__(256) void k_transpose(const float* __restrict__ src,
                                                   _Float16* __restrict__ dst,
                                                   int K, int C, int dstStride){
    __shared__ float tile[32][33];
    const int tid = threadIdx.x;
    const int c0 = blockIdx.x*32, k0 = blockIdx.y*32;
    const int cl = tid & 31, r8 = tid >> 5;
    #pragma unroll
    for(int i=0;i<4;i++){
        const int k = k0 + r8 + i*8;
        if(k < K && c0+cl < C) tile[r8 + i*8][cl] = src[(size_t)k*C + c0 + cl];
    }
    __syncthreads();
    const int kl = tid & 31, c8 = tid >> 5;
    #pragma unroll
    for(int i=0;i<4;i++){
        const int c = c0 + c8 + i*8;
        if(c < C && k0+kl < K) dst[(size_t)c*dstStride + k0 + kl] = (_Float16)tile[kl][c8 + i*8];
    }
}

// proc_enc[b,t,:] = inputs[b,t,:] @ W_enc  -> fp16.  One block per (b,t) row.
__global__ __launch_bounds__(128) void k_proc_enc(const float* __restrict__ inputs,
                                                  const float* __restrict__ Wenc,
                                                  __half* __restrict__ pe_h){
    const int row = blockIdx.x;
    const int a   = threadIdx.x;
    const float* in = inputs + (size_t)row*EE;
    float acc = 0.f;
    for(int k=0;k<EE;k++) acc = fmaf(in[k], Wenc[k*AA + a], acc);
    pe_h[(size_t)row*AA + a] = __float2half(acc);
}

// PIP[b][t][m] = inputs[b][t][:] @ Wp_c[:,m]   (ctx half of output projection)
__global__ __launch_bounds__(320) void k_pip(const float* __restrict__ inputs,
                                             const float* __restrict__ Wp_c,
                                             __half* __restrict__ PIP){
    const int b = blockIdx.x >> 6, t4 = (blockIdx.x & 63)*4;
    __shared__ float xs[4*EE];
    const int tid = threadIdx.x;
    for(int i=tid; i<4*EE; i+=320) xs[i] = inputs[((size_t)b*TENC + t4)*EE + i];
    __syncthreads();
    const int tl = tid/80, m = tid%80;
    float acc = 0.f;
    for(int k=0;k<EE;k++) acc = fmaf(xs[tl*EE + k], Wp_c[k*NM + m], acc);
    PIP[((size_t)b*TENC + t4 + tl)*NM + m] = __float2half(acc);
}

// prenet for all t: xT[t][k][b]. One block per t.
__global__ __launch_bounds__(256) void k_prenet(const float* __restrict__ pmels,
                                                const float* __restrict__ pw1, const float* __restrict__ pb1,
                                                const float* __restrict__ pw2, const float* __restrict__ pb2,
                                                float* __restrict__ xT){
    const int t = blockIdx.x;
    __shared__ float pm[BB*NM];
    __shared__ float h1s[BB*256];
    const int tid = threadIdx.x;
    for(int el=tid; el<BB*NM; el+=256){
        const int b = el/NM, m = el%NM;
        pm[el] = (t==0) ? 0.f : pmels[(size_t)(b*NM + m)*TDEC + (t-1)];
    }
    __syncthreads();
    const int a = tid;
    float acc[BB];
    #pragma unroll
    for(int b=0;b<BB;b++) acc[b]=0.f;
    for(int m=0;m<NM;m++){
        const float w = pw1[m*256 + a];
        #pragma unroll
        for(int b=0;b<BB;b++) acc[b] = fmaf(pm[b*NM+m], w, acc[b]);
    }
    {
        const float bias = pb1[a];
        for(int b=0;b<BB;b++) h1s[b*256+a] = fmaxf(acc[b]+bias, 0.f);
    }
    __syncthreads();
    #pragma unroll
    for(int b=0;b<BB;b++) acc[b]=0.f;
    for(int k=0;k<256;k++){
        const float w = pw2[k*256 + a];
        #pragma unroll
        for(int b=0;b<BB;b++) acc[b] = fmaf(h1s[b*256+k], w, acc[b]);
    }
    {
        const float bias = pb2[a];
        float* dst = xT + ((size_t)t*256 + a)*BB;
        #pragma unroll
        for(int b=0;b<BB;b++) dst[b] = fmaxf(acc[b]+bias, 0.f);
    }
}

// Mloc[d][a] and cbp[a]
__global__ void k_mloc(const float* __restrict__ conv_w, const float* __restrict__ conv_b,
                       const float* __restrict__ W_loc, float* __restrict__ Mloc, float* __restrict__ cbp){
    const int a = threadIdx.x;
    for(int d=0; d<31; d++){
        float s = 0.f;
        for(int ch=0; ch<32; ch++) s = fmaf(conv_w[ch*31 + d], W_loc[ch*AA + a], s);
        Mloc[d*AA + a] = s;
    }
    float s = 0.f;
    for(int ch=0; ch<32; ch++) s = fmaf(conv_b[ch], W_loc[ch*AA + a], s);
    cbp[a] = s;
}

// ---------------- per-step kernels ----------------

// Fused gate-GEMM + LSTM cell; fp16 col-major weights WT[4096][K].
// Block = 2 cells x 4 gates (8 cols). Thread = (col 8, kp 32). acc over 32 batch.
__global__ __launch_bounds__(256) void k_gemm_lstm(
    const float* __restrict__ in0, int len0,
    const float* __restrict__ in1, int len1,
    const float* __restrict__ in2, int len2,
    const _Float16* __restrict__ WT, int K, const float* __restrict__ bias,
    float* __restrict__ cst, float* __restrict__ hT)
{
    __shared__ float part[8*33*36];   // [col][b pad33][kp pad36] = 38016 B
    __shared__ float gsum[8*32];
    const int tid = threadIdx.x;
    const int col = tid & 7;          // g = col>>1, ci = col&1
    const int kp  = tid >> 3;         // 0..31
    const int g = col >> 1, ci = col & 1;
    const int cell = blockIdx.x*2 + ci;
    const _Float16* wp = WT + (size_t)(g*HH + cell)*K;
    const int kchunk = K >> 5;
    const int k0 = kp*kchunk, k1 = k0 + kchunk;

    float acc[32];
    #pragma unroll
    for(int j=0;j<32;j++) acc[j]=0.f;

    const float* ins[3]  = {in0,in1,in2};
    const int    lens[3] = {len0,len1,len2};
    int base = 0;
    for(int s=0;s<3;s++){
        const int len = lens[s];
        if(len == 0) break;
        const int segEnd = base + len;
        const int lo = (k0 > base) ? k0 : base;
        const int hi = (k1 < segEnd) ? k1 : segEnd;
        const float* xin = ins[s];
        for(int kb=lo; kb<hi; kb+=8){
            const h8 w8 = *(const h8*)(wp + kb);
            #pragma unroll
            for(int i=0;i<8;i++){
                const float w = (float)w8[i];
                const float4* xv = (const float4*)(xin + (size_t)(kb + i - base)*BB);
                #pragma unroll
                for(int j=0;j<8;j++){
                    const float4 v = xv[j];
                    acc[4*j+0] = fmaf(w, v.x, acc[4*j+0]);
                    acc[4*j+1] = fmaf(w, v.y, acc[4*j+1]);
                    acc[4*j+2] = fmaf(w, v.z, acc[4*j+2]);
                    acc[4*j+3] = fmaf(w, v.w, acc[4*j+3]);
                }
            }
        }
        base = segEnd;
    }
    {
        float* pd = part + col*1188 + kp;   // + b*36
        #pragma unroll
        for(int b=0;b<32;b++) pd[b*36] = acc[b];
    }
    __syncthreads();
    // reduce over kp: 256 threads = (c2 8, b2 32)
    {
        const int c2 = tid >> 5, b2 = tid & 31;
        const float4* pr = (const float4*)(part + c2*1188 + b2*36);
        float4 s4 = pr[0];
        #pragma unroll
        for(int j=1;j<8;j++){
            const float4 v = pr[j];
            s4.x += v.x; s4.y += v.y; s4.z += v.z; s4.w += v.w;
        }
        gsum[c2*32 + b2] = (s4.x + s4.y) + (s4.z + s4.w);
    }
    __syncthreads();
    if(tid < 64){
        const int b = tid & 31, ci2 = tid >> 5;
        const int cell2 = blockIdx.x*2 + ci2;
        float gs[4];
        #pragma unroll
        for(int gg2=0; gg2<4; gg2++)
            gs[gg2] = gsum[(gg2*2 + ci2)*32 + b] + bias[gg2*HH + cell2];
        const float ig = sigf(gs[0]);
        const float fg = sigf(gs[1]);
        const float gv = tanhfast(gs[2]);
        const float og = sigf(gs[3]);
        const int idx = cell2*BB + b;
        const float cn = fg*cst[idx] + ig*gv;
        cst[idx] = cn;
        hT[idx]  = og*tanhfast(cn);
    }
}

// q (blocks 0..31, cols 0..127) and out_h2 (+bp -> d_out) (blocks 32..51, cols 128..207).
// WqoT fp16 [208][1024]; X = h2T fp32 [k][32].
__global__ __launch_bounds__(256) void k_qout(const float* __restrict__ h2T,
                                              const _Float16* __restrict__ WqoT,
                                              const float* __restrict__ bp,
                                              float* __restrict__ q_ws,
                                              float* __restrict__ out, int t)
{
    __shared__ float part[4*33*68];   // [c][b pad33][kp pad68] = 35904 B
    const int tid = threadIdx.x;
    const int c  = tid & 3;
    const int kp = tid >> 2;          // 0..63
    const int colbase = (blockIdx.x < 32) ? blockIdx.x*4 : 128 + (blockIdx.x - 32)*4;
    const _Float16* wp = WqoT + (size_t)(colbase + c)*1024;

    float acc[32];
    #pragma unroll
    for(int j=0;j<32;j++) acc[j]=0.f;
    const int k0 = kp*16;
    for(int kb=k0; kb<k0+16; kb+=8){
        const h8 w8 = *(const h8*)(wp + kb);
        #pragma unroll
        for(int i=0;i<8;i++){
            const float w = (float)w8[i];
            const float4* xv = (const float4*)(h2T + (size_t)(kb + i)*BB);
            #pragma unroll
            for(int j=0;j<8;j++){
                const float4 v = xv[j];
                acc[4*j+0] = fmaf(w, v.x, acc[4*j+0]);
                acc[4*j+1] = fmaf(w, v.y, acc[4*j+1]);
                acc[4*j+2] = fmaf(w, v.z, acc[4*j+2]);
                acc[4*j+3] = fmaf(w, v.w, acc[4*j+3]);
            }
        }
    }
    {
        float* pd = part + c*2244 + kp;   // + b*68
        #pragma unroll
        for(int b=0;b<32;b++) pd[b*68] = acc[b];
    }
    __syncthreads();
    if(tid < 128){
        const int c2 = tid >> 5, b2 = tid & 31;
        const float4* pr = (const float4*)(part + c2*2244 + b2*68);
        float4 s4 = pr[0];
        #pragma unroll
        for(int j=1;j<16;j++){
            const float4 v = pr[j];
            s4.x += v.x; s4.y += v.y; s4.z += v.z; s4.w += v.w;
        }
        const float s = (s4.x + s4.y) + (s4.z + s4.w);
        if(blockIdx.x < 32){
            q_ws[b2*AA + colbase + c2] = s;
        } else {
            const int m = colbase - 128 + c2;
            out[((size_t)t*BB + b2)*NM + m] = s + bp[m];
        }
    }
}

// energies[b,t] = sum_a tanh(q[a]+cbp[a]+pe[b,t,a]+conv)*v_e[a]; 128 blocks.
__global__ __launch_bounds__(256) void k_energy(
    const float* __restrict__ q_ws, const float* __restrict__ cbp,
    const float* __restrict__ MlocG, const float* __restrict__ v_e,
    const float* __restrict__ awc, const __half* __restrict__ pe_h,
    float* __restrict__ e_ws)
{
    const int b = blockIdx.x & 31, quarter = blockIdx.x >> 5;
    const int t0 = quarter*64;
    __shared__ float qc[AA], ml[31*AA], ve[AA], awin[94], epart[256];
    const int tid = threadIdx.x;
    if(tid < AA){ qc[tid] = q_ws[b*AA+tid] + cbp[tid]; ve[tid] = v_e[tid]; }
    for(int i=tid; i<31*AA; i+=256) ml[i] = MlocG[i];
    if(tid < 94){
        const int g = t0 - 15 + tid;
        awin[tid] = (g>=0 && g<TENC) ? awc[b*TENC+g] : 0.f;
    }
    __syncthreads();
    const int tl = tid & 63, aq = tid >> 6;
    const int t  = t0 + tl;
    float awr[31];
    #pragma unroll
    for(int d=0;d<31;d++) awr[d] = awin[tl+d];
    float s[32];
    const __half* pe = pe_h + ((size_t)(b*TENC+t))*AA + aq*32;
    #pragma unroll
    for(int j=0;j<32;j++) s[j] = qc[aq*32+j] + __half2float(pe[j]);
    for(int d=0;d<31;d++){
        const float w = awr[d];
        const float4* m4 = (const float4*)&ml[d*AA + aq*32];
        #pragma unroll
        for(int jj=0;jj<8;jj++){
            const float4 v = m4[jj];
            s[4*jj+0] = fmaf(w, v.x, s[4*jj+0]);
            s[4*jj+1] = fmaf(w, v.y, s[4*jj+1]);
            s[4*jj+2] = fmaf(w, v.z, s[4*jj+2]);
            s[4*jj+3] = fmaf(w, v.w, s[4*jj+3]);
        }
    }
    float esum = 0.f;
    #pragma unroll
    for(int j=0;j<32;j++) esum = fmaf(tanhfast(s[j]), ve[aq*32+j], esum);
    epart[aq*64 + tl] = esum;
    __syncthreads();
    if(tid < 64){
        const float e2 = epart[tid] + epart[64+tid] + epart[128+tid] + epart[192+tid];
        e_ws[b*TENC + t0 + tid] = e2;
    }
}

// softmax + aw_cum + ctx (->ctxT) + ctx-projection partial (atomicAdd into out).
// 128 blocks = (b 32) x (quarter 4).
__global__ __launch_bounds__(256) void k_attn(
    const float* __restrict__ e_ws, const __half* __restrict__ inputs_h,
    const __half* __restrict__ PIP, float* __restrict__ awc,
    float* __restrict__ ctxT, float* __restrict__ out, int t)
{
    const int b = blockIdx.x & 31, quarter = blockIdx.x >> 5;
    const int tid = threadIdx.x;
    __shared__ float aw_s[TENC], sred[8];
    const float e = e_ws[b*TENC + tid];
    float m = e;
    #pragma unroll
    for(int o=32;o>=1;o>>=1) m = fmaxf(m, __shfl_xor(m, o));
    if((tid&63)==0) sred[tid>>6] = m;
    __syncthreads();
    m = fmaxf(fmaxf(sred[0],sred[1]), fmaxf(sred[2],sred[3]));
    const float p = __expf(e - m);
    float sum = p;
    #pragma unroll
    for(int o=32;o>=1;o>>=1) sum += __shfl_xor(sum, o);
    if((tid&63)==0) sred[4+(tid>>6)] = sum;
    __syncthreads();
    sum = sred[4]+sred[5]+sred[6]+sred[7];
    const float awv = p/sum;
    aw_s[tid] = awv;
    __syncthreads();
    if(tid < 64) awc[b*TENC + quarter*64 + tid] += aw_s[quarter*64 + tid];
    if(tid < 128){
        const int cglob = quarter*128 + tid;
        const __half* ib = inputs_h + (size_t)b*TENC*EE + cglob;
        float a0 = 0.f;
        #pragma unroll 4
        for(int tt=0; tt<TENC; tt++)
            a0 = fmaf(aw_s[tt], __half2float(ib[(size_t)tt*EE]), a0);
        ctxT[(size_t)cglob*BB + b] = a0;
    } else if(tid < 208){
        const int mm = tid - 128;
        const __half* pb_ = PIP + ((size_t)b*TENC + quarter*64)*NM + mm;
        float s2 = 0.f;
        #pragma unroll 4
        for(int tt=0; tt<64; tt++)
            s2 = fmaf(aw_s[quarter*64 + tt], __half2float(pb_[(size_t)tt*NM]), s2);
        atomicAdd(&out[((size_t)t*BB + b)*NM + mm], s2);
    }
}

// ---------------- host ----------------

extern "C" void kernel_launch(void* const* d_in, const int* in_sizes, int n_in,
                              void* d_out, int out_size, void* d_ws, size_t ws_size,
                              hipStream_t stream)
{
    const float* inputs = (const float*)d_in[0];
    const float* pmels  = (const float*)d_in[1];
    const float* W_enc  = (const float*)d_in[2];
    const float* W_q    = (const float*)d_in[3];
    const float* conv_w = (const float*)d_in[4];
    const float* conv_b = (const float*)d_in[5];
    const float* W_loc  = (const float*)d_in[6];
    const float* v_e    = (const float*)d_in[7];
    const float* pw1    = (const float*)d_in[8];
    const float* pb1    = (const float*)d_in[9];
    const float* pw2    = (const float*)d_in[10];
    const float* pb2    = (const float*)d_in[11];
    const float* Wi1    = (const float*)d_in[12];
    const float* Wh1    = (const float*)d_in[13];
    const float* bl1    = (const float*)d_in[14];
    const float* Wi2    = (const float*)d_in[15];
    const float* Wh2    = (const float*)d_in[16];
    const float* bl2    = (const float*)d_in[17];
    const float* Wp     = (const float*)d_in[18];
    const float* bp     = (const float*)d_in[19];
    float* out = (float*)d_out;
    (void)in_sizes; (void)n_in; (void)out_size; (void)ws_size;

    char* ws = (char*)d_ws;
    size_t off = 0;
    auto carve = [&](size_t bytes)->char* {
        char* p = ws + off;
        off += (bytes + 255) & ~(size_t)255;
        return p;
    };
    __half*    inputs_h = (__half*)   carve((size_t)BB*TENC*EE*2);
    __half*    pe_h     = (__half*)   carve((size_t)BB*TENC*AA*2);
    float*     xT       = (float*)    carve((size_t)TDEC*256*BB*4);
    _Float16*  W1T      = (_Float16*) carve((size_t)GG*1792*2);
    _Float16*  W2T      = (_Float16*) carve((size_t)GG*2048*2);
    _Float16*  WqoT     = (_Float16*) carve((size_t)208*1024*2);
    __half*    PIP      = (__half*)   carve((size_t)BB*TENC*NM*2);
    const int NSTATE = 16384 + 4*32768 + 2*32768 + 8192;
    float* states = (float*)carve((size_t)NSTATE*4);
    float* ctxT = states;
    float* h1a  = states + 16384;
    float* h1b  = states + 49152;
    float* h2a  = states + 81920;
    float* h2b  = states + 114688;
    float* c1   = states + 147456;
    float* c2   = states + 180224;
    float* awc  = states + 212992;
    float* q_ws = (float*)carve((size_t)BB*AA*4);
    float* e_ws = (float*)carve((size_t)BB*TENC*4);
    float* Mloc = (float*)carve((size_t)31*AA*4);
    float* cbp  = (float*)carve((size_t)AA*4);

    // ---- one-time (per launch) precompute ----
    k_cvt_half<<<2048,256,0,stream>>>(inputs, inputs_h, BB*TENC*EE);
    k_proc_enc<<<BB*TENC,128,0,stream>>>(inputs, W_enc, pe_h);
    k_prenet<<<TDEC,256,0,stream>>>(pmels, pw1,pb1,pw2,pb2, xT);
    k_mloc<<<1,128,0,stream>>>(conv_w, conv_b, W_loc, Mloc, cbp);
    k_zero<<<(NSTATE+255)/256,256,0,stream>>>(states, NSTATE);
    // weight transposes -> fp16 col-major
    k_transpose<<<dim3(GG/32, 768/32),256,0,stream>>>(Wi1, W1T,        768, GG, 1792);
    k_transpose<<<dim3(GG/32,1024/32),256,0,stream>>>(Wh1, W1T+768,   1024, GG, 1792);
    k_transpose<<<dim3(GG/32,1024/32),256,0,stream>>>(Wi2, W2T,       1024, GG, 2048);
    k_transpose<<<dim3(GG/32,1024/32),256,0,stream>>>(Wh2, W2T+1024,  1024, GG, 2048);
    k_transpose<<<dim3(AA/32,1024/32),256,0,stream>>>(W_q, WqoT,      1024, AA, 1024);
    k_transpose<<<dim3(3,     1024/32),256,0,stream>>>(Wp,  WqoT + (size_t)128*1024, 1024, NM, 1024);
    k_pip<<<BB*64,320,0,stream>>>(inputs, Wp + (size_t)HH*NM, PIP);

    // ---- sequential decode ----
    for(int t=0; t<TDEC; t++){
        float* h1wr = (t&1) ? h1b : h1a;
        float* h1rd = (t&1) ? h1a : h1b;
        float* h2wr = (t&1) ? h2b : h2a;
        float* h2rd = (t&1) ? h2a : h2b;

        k_gemm_lstm<<<512,256,0,stream>>>(xT + (size_t)t*256*BB, 256,
                                          ctxT, 512, h1rd, 1024,
                                          W1T, 1792, bl1, c1, h1wr);
        k_gemm_lstm<<<512,256,0,stream>>>(h1wr, 1024, h2rd, 1024,
                                          (const float*)nullptr, 0,
                                          W2T, 2048, bl2, c2, h2wr);
        k_qout<<<52,256,0,stream>>>(h2wr, WqoT, bp, q_ws, out, t);
        k_energy<<<128,256,0,stream>>>(q_ws, cbp, Mloc, v_e, awc, pe_h, e_ws);
        k_attn<<<128,256,0,stream>>>(e_ws, inputs_h, PIP, awc, ctxT, out, t);
    }
}

// Round 7
// 20924.509 us; speedup vs baseline: 1.9859x; 1.1111x over previous
//
#include <hip/hip_runtime.h>
#include <hip/hip_fp16.h>

#define BB   32
#define TENC 256
#define EE   512
#define TDEC 200
#define NM   80
#define HH   1024
#define AA   128
#define GG   4096
#define K1   1792   // x(256)|ctx(512)|h1(1024)
#define K2   2048   // h1|h2

typedef _Float16 h8v __attribute__((ext_vector_type(8)));

__device__ __forceinline__ float sigf(float x){ return 1.0f/(1.0f + __expf(-x)); }
__device__ __forceinline__ float tanhfast(float x){ return 1.0f - 2.0f/(1.0f + __expf(2.0f*x)); }

// ---------------- precompute kernels ----------------

__global__ void k_zero(float* __restrict__ p, int n){
    int i = blockIdx.x*blockDim.x + threadIdx.x;
    if(i < n) p[i] = 0.f;
}

__global__ void k_cvt_half(const float* __restrict__ src, __half* __restrict__ dst, int n){
    int i = blockIdx.x*blockDim.x + threadIdx.x;
    int stride = gridDim.x*blockDim.x;
    for(; i<n; i+=stride) dst[i] = __float2half(src[i]);
}

// transpose fp32 src[k][c] -> fp16 dst[p][kOff+k]; pack=1 remaps c (gate*1024+cell) -> p=cell*4+gate
__global__ __launch_bounds__(256) void k_transpose2(const float* __restrict__ src,
                                                    _Float16* __restrict__ dst,
                                                    int K, int C, int dstStride, int kOff, int pack){
    __shared__ float tile[32][33];
    const int tid = threadIdx.x;
    const int c0 = blockIdx.x*32, k0 = blockIdx.y*32;
    const int cl = tid & 31, r8 = tid >> 5;
    #pragma unroll
    for(int i=0;i<4;i++){
        const int k = k0 + r8 + i*8;
        if(k < K && c0+cl < C) tile[r8 + i*8][cl] = src[(size_t)k*C + c0 + cl];
    }
    __syncthreads();
    const int kl = tid & 31, c8 = tid >> 5;
    #pragma unroll
    for(int i=0;i<4;i++){
        const int c = c0 + c8 + i*8;
        if(c < C && k0+kl < K){
            const int p = pack ? ((c & 1023)*4 + (c >> 10)) : c;
            dst[(size_t)p*dstStride + kOff + k0 + kl] = (_Float16)tile[kl][c8 + i*8];
        }
    }
}

__global__ __launch_bounds__(128) void k_proc_enc(const float* __restrict__ inputs,
                                                  const float* __restrict__ Wenc,
                                                  __half* __restrict__ pe_h){
    const int row = blockIdx.x;
    const int a   = threadIdx.x;
    const float* in = inputs + (size_t)row*EE;
    float acc = 0.f;
    for(int k=0;k<EE;k++) acc = fmaf(in[k], Wenc[k*AA + a], acc);
    pe_h[(size_t)row*AA + a] = __float2half(acc);
}

__global__ __launch_bounds__(320) void k_pip(const float* __restrict__ inputs,
                                             const float* __restrict__ Wp_c,
                                             __half* __restrict__ PIP){
    const int b = blockIdx.x >> 6, t4 = (blockIdx.x & 63)*4;
    __shared__ float xs[4*EE];
    const int tid = threadIdx.x;
    for(int i=tid; i<4*EE; i+=320) xs[i] = inputs[((size_t)b*TENC + t4)*EE + i];
    __syncthreads();
    const int tl = tid/80, m = tid%80;
    float acc = 0.f;
    for(int k=0;k<EE;k++) acc = fmaf(xs[tl*EE + k], Wp_c[k*NM + m], acc);
    PIP[((size_t)b*TENC + t4 + tl)*NM + m] = __float2half(acc);
}

// prenet for all t -> XS1 rows [t][b][0:256] (row stride K1)
__global__ __launch_bounds__(256) void k_prenet(const float* __restrict__ pmels,
                                                const float* __restrict__ pw1, const float* __restrict__ pb1,
                                                const float* __restrict__ pw2, const float* __restrict__ pb2,
                                                float* __restrict__ XS1){
    const int t = blockIdx.x;
    __shared__ float pm[BB*NM];
    __shared__ float h1s[BB*256];
    const int tid = threadIdx.x;
    for(int el=tid; el<BB*NM; el+=256){
        const int b = el/NM, m = el%NM;
        pm[el] = (t==0) ? 0.f : pmels[(size_t)(b*NM + m)*TDEC + (t-1)];
    }
    __syncthreads();
    const int a = tid;
    float acc[BB];
    #pragma unroll
    for(int b=0;b<BB;b++) acc[b]=0.f;
    for(int m=0;m<NM;m++){
        const float w = pw1[m*256 + a];
        #pragma unroll
        for(int b=0;b<BB;b++) acc[b] = fmaf(pm[b*NM+m], w, acc[b]);
    }
    {
        const float bias = pb1[a];
        for(int b=0;b<BB;b++) h1s[b*256+a] = fmaxf(acc[b]+bias, 0.f);
    }
    __syncthreads();
    #pragma unroll
    for(int b=0;b<BB;b++) acc[b]=0.f;
    for(int k=0;k<256;k++){
        const float w = pw2[k*256 + a];
        #pragma unroll
        for(int b=0;b<BB;b++) acc[b] = fmaf(h1s[b*256+k], w, acc[b]);
    }
    {
        const float bias = pb2[a];
        #pragma unroll
        for(int b=0;b<BB;b++)
            XS1[((size_t)t*BB + b)*K1 + a] = fmaxf(acc[b]+bias, 0.f);
    }
}

__global__ void k_mloc(const float* __restrict__ conv_w, const float* __restrict__ conv_b,
                       const float* __restrict__ W_loc, float* __restrict__ Mloc, float* __restrict__ cbp){
    const int a = threadIdx.x;
    for(int d=0; d<31; d++){
        float s = 0.f;
        for(int ch=0; ch<32; ch++) s = fmaf(conv_w[ch*31 + d], W_loc[ch*AA + a], s);
        Mloc[d*AA + a] = s;
    }
    float s = 0.f;
    for(int ch=0; ch<32; ch++) s = fmaf(conv_b[ch], W_loc[ch*AA + a], s);
    cbp[a] = s;
}

// ---------------- per-step kernels ----------------

// Fused GEMM + LSTM cell. X = XS[32][K] row-major (contiguous). WT fp16 [4096 packed p=cell*4+gate][K].
// grid 256 blocks (16 packed cols each = 4 cells), 512 threads: b=tid&31, cs=(tid>>5)&1, kp=tid>>6.
__global__ __launch_bounds__(512) void k_lstm(
    const float* __restrict__ XS, const _Float16* __restrict__ WT, int K,
    const float* __restrict__ bias, float* __restrict__ cst,
    float* __restrict__ houtA, int strideA, int offA,
    float* __restrict__ houtB, int strideB, int offB)
{
    __shared__ float smem[8320];   // xs chunk [32][260]; reused for partials after last sync
    const int tid = threadIdx.x, bid = blockIdx.x;
    const int b = tid & 31, cs = (tid>>5)&1, kp = tid>>6;
    float acc[8];
    #pragma unroll
    for(int j=0;j<8;j++) acc[j]=0.f;
    const _Float16* wbase = WT + (size_t)(bid*16 + cs*8)*K;

    for(int ck=0; ck<K; ck+=256){
        // stage 32x256 chunk of X into LDS (coalesced float4)
        for(int r=tid; r<2048; r+=512){
            const int bb = r >> 6, kq = (r & 63)*4;
            *(float4*)&smem[bb*260 + kq] = *(const float4*)(XS + (size_t)bb*K + ck + kq);
        }
        __syncthreads();
        const float* xrow = smem + b*260 + kp*32;
        const _Float16* wk = wbase + ck + kp*32;
        #pragma unroll
        for(int kb=0; kb<32; kb+=8){
            const float4 xa = *(const float4*)(xrow + kb);
            const float4 xb = *(const float4*)(xrow + kb + 4);
            #pragma unroll
            for(int j=0;j<8;j++){
                const h8v w8 = *(const h8v*)(wk + (size_t)j*K + kb);
                acc[j] = fmaf((float)w8[0], xa.x, acc[j]);
                acc[j] = fmaf((float)w8[1], xa.y, acc[j]);
                acc[j] = fmaf((float)w8[2], xa.z, acc[j]);
                acc[j] = fmaf((float)w8[3], xa.w, acc[j]);
                acc[j] = fmaf((float)w8[4], xb.x, acc[j]);
                acc[j] = fmaf((float)w8[5], xb.y, acc[j]);
                acc[j] = fmaf((float)w8[6], xb.z, acc[j]);
                acc[j] = fmaf((float)w8[7], xb.w, acc[j]);
            }
        }
        __syncthreads();
    }
    // partials: smem[(col*32+b) + 512*kp], col = cs*8+j
    #pragma unroll
    for(int j=0;j<8;j++) smem[(cs*8+j)*32 + b + 512*kp] = acc[j];
    __syncthreads();
    {
        // tid = col*32+b: sum 8 kp partials + bias
        float s = 0.f;
        #pragma unroll
        for(int q=0;q<8;q++) s += smem[tid + 512*q];
        const int p = bid*16 + (tid>>5);   // packed col: cell*4+gate
        __syncthreads();
        smem[4608 + tid] = s + bias[(p & 3)*HH + (p >> 2)];
    }
    __syncthreads();
    if(tid < 128){
        const int cl = tid>>5, bb = tid&31;
        const float gi = smem[4608 + (cl*4+0)*32 + bb];
        const float gf = smem[4608 + (cl*4+1)*32 + bb];
        const float gg = smem[4608 + (cl*4+2)*32 + bb];
        const float go = smem[4608 + (cl*4+3)*32 + bb];
        const int cell = bid*4 + cl;
        const int ci = cell*BB + bb;
        const float cn = sigf(gf)*cst[ci] + sigf(gi)*tanhfast(gg);
        cst[ci] = cn;
        const float hv = sigf(go)*tanhfast(cn);
        houtA[(size_t)bb*strideA + offA + cell] = hv;
        if(houtB) houtB[(size_t)bb*strideB + offB + cell] = hv;
    }
}

// q (redundant per b) + energies for a 32-t slice. grid 256: b=bid>>3, ts=bid&7. 256 threads.
__global__ __launch_bounds__(256) void k_qe(
    const float* __restrict__ XS2cur,   // [32][2048]; h2 at +1024
    const _Float16* __restrict__ WqT, const float* __restrict__ cbp,
    const float* __restrict__ Mloc, const float* __restrict__ ve,
    const float* __restrict__ awc, const __half* __restrict__ pe,
    float* __restrict__ e_ws)
{
    const int b = blockIdx.x >> 3, ts = blockIdx.x & 7;
    const int t0 = ts*32;
    const int tid = threadIdx.x;
    __shared__ float h2s[1024], qc[256], qf[128], ml[31*AA], ves[AA], awin[64], ep[256];
    for(int i=tid; i<1024; i+=256) h2s[i] = XS2cur[(size_t)b*2048 + 1024 + i];
    for(int i=tid; i<31*AA; i+=256) ml[i] = Mloc[i];
    if(tid < AA) ves[tid] = ve[tid];
    if(tid < 62){
        const int g = t0 - 15 + tid;
        awin[tid] = (g>=0 && g<TENC) ? awc[b*TENC+g] : 0.f;
    }
    __syncthreads();
    {   // q[a] = h2 . WqT[a][:]
        const int a = tid & 127, tp = tid >> 7;
        float qa = 0.f;
        const _Float16* wq = WqT + (size_t)a*HH + tp*512;
        const float* hs = h2s + tp*512;
        for(int kb=0; kb<512; kb+=8){
            const h8v w8 = *(const h8v*)(wq + kb);
            #pragma unroll
            for(int i2=0;i2<8;i2++) qa = fmaf((float)w8[i2], hs[kb+i2], qa);
        }
        qc[tp*AA + a] = qa;
    }
    __syncthreads();
    if(tid < AA) qf[tid] = qc[tid] + qc[AA+tid] + cbp[tid];
    __syncthreads();
    {   // energies: thread (tl 32, aq 8) covers a-range aq*16..+16 for t0+tl
        const int tl = tid & 31, aq = tid >> 5;
        const int a0 = aq*16;
        const int t  = t0 + tl;
        float s[16];
        const __half* pp = pe + ((size_t)(b*TENC + t))*AA + a0;
        #pragma unroll
        for(int j=0;j<16;j++) s[j] = qf[a0+j] + __half2float(pp[j]);
        for(int d=0;d<31;d++){
            const float w = awin[tl+d];
            #pragma unroll
            for(int j=0;j<16;j++) s[j] = fmaf(w, ml[d*AA + a0 + j], s[j]);
        }
        float es = 0.f;
        #pragma unroll
        for(int j=0;j<16;j++) es = fmaf(tanhfast(s[j]), ves[a0+j], es);
        ep[aq*32 + tl] = es;
    }
    __syncthreads();
    if(tid < 32){
        float e = 0.f;
        #pragma unroll
        for(int q=0;q<8;q++) e += ep[q*32 + tid];
        e_ws[b*TENC + t0 + tid] = e;
    }
}

// softmax + awc + ctx (-> next XS1 row) + full output projection. grid 32 (b=bid), 256 threads.
__global__ __launch_bounds__(256) void k_attn(
    const float* __restrict__ e_ws, const __half* __restrict__ inputs_h,
    const __half* __restrict__ PIP, float* __restrict__ awc,
    float* __restrict__ XS1next,       // ctx -> [b][256:768] (row stride K1)
    const float* __restrict__ XS2cur,  // h2 at [b][1024:2048]
    const _Float16* __restrict__ WohT, const float* __restrict__ bp,
    float* __restrict__ out, int t)
{
    const int b = blockIdx.x, tid = threadIdx.x;
    __shared__ float aw[TENC], h2s[1024], red[320], sred[8];
    for(int i=tid; i<1024; i+=256) h2s[i] = XS2cur[(size_t)b*2048 + 1024 + i];
    const float e = e_ws[b*TENC + tid];
    float m = e;
    #pragma unroll
    for(int o=32;o>=1;o>>=1) m = fmaxf(m, __shfl_xor(m, o));
    if((tid&63)==0) sred[tid>>6] = m;
    __syncthreads();
    m = fmaxf(fmaxf(sred[0],sred[1]), fmaxf(sred[2],sred[3]));
    const float p = __expf(e - m);
    float sum = p;
    #pragma unroll
    for(int o=32;o>=1;o>>=1) sum += __shfl_xor(sum, o);
    if((tid&63)==0) sred[4+(tid>>6)] = sum;
    __syncthreads();
    sum = sred[4]+sred[5]+sred[6]+sred[7];
    const float awv = p/sum;
    aw[tid] = awv;
    awc[b*TENC + tid] += awv;
    __syncthreads();
    // ctx: channels tid and tid+256
    {
        float a0=0.f, a1=0.f;
        const __half* ib = inputs_h + (size_t)b*TENC*EE;
        for(int tt=0; tt<TENC; tt+=4){
            const float4 w4 = *(const float4*)&aw[tt];
            a0 = fmaf(w4.x, __half2float(ib[(size_t)(tt+0)*EE + tid]),       a0);
            a1 = fmaf(w4.x, __half2float(ib[(size_t)(tt+0)*EE + 256 + tid]), a1);
            a0 = fmaf(w4.y, __half2float(ib[(size_t)(tt+1)*EE + tid]),       a0);
            a1 = fmaf(w4.y, __half2float(ib[(size_t)(tt+1)*EE + 256 + tid]), a1);
            a0 = fmaf(w4.z, __half2float(ib[(size_t)(tt+2)*EE + tid]),       a0);
            a1 = fmaf(w4.z, __half2float(ib[(size_t)(tt+2)*EE + 256 + tid]), a1);
            a0 = fmaf(w4.w, __half2float(ib[(size_t)(tt+3)*EE + tid]),       a0);
            a1 = fmaf(w4.w, __half2float(ib[(size_t)(tt+3)*EE + 256 + tid]), a1);
        }
        float* xrow = XS1next + (size_t)b*K1 + 256;
        xrow[tid]       = a0;
        xrow[256 + tid] = a1;
    }
    // output: s1 = h2 @ WohT (tid<160: m, kh halves of K) then s2 = aw . PIP (same threads)
    if(tid < 160){
        const int m2 = tid % 80, kh = tid / 80;
        float s1 = 0.f;
        const _Float16* wo = WohT + (size_t)m2*HH + kh*512;
        const float* hs = h2s + kh*512;
        for(int kb=0; kb<512; kb+=8){
            const h8v w8 = *(const h8v*)(wo + kb);
            #pragma unroll
            for(int i2=0;i2<8;i2++) s1 = fmaf((float)w8[i2], hs[kb+i2], s1);
        }
        red[kh*80 + m2] = s1;
        float s2 = 0.f;
        const __half* pp = PIP + ((size_t)(b*TENC) + kh*128)*NM + m2;
        const float* awp = aw + kh*128;
        for(int tt=0; tt<128; tt++) s2 = fmaf(awp[tt], __half2float(pp[(size_t)tt*NM]), s2);
        red[160 + kh*80 + m2] = s2;
    }
    __syncthreads();
    if(tid < NM){
        const float o = red[tid] + red[80+tid] + red[160+tid] + red[240+tid] + bp[tid];
        out[((size_t)t*BB + b)*NM + tid] = o;
    }
}

// ---------------- host ----------------

extern "C" void kernel_launch(void* const* d_in, const int* in_sizes, int n_in,
                              void* d_out, int out_size, void* d_ws, size_t ws_size,
                              hipStream_t stream)
{
    const float* inputs = (const float*)d_in[0];
    const float* pmels  = (const float*)d_in[1];
    const float* W_enc  = (const float*)d_in[2];
    const float* W_q    = (const float*)d_in[3];
    const float* conv_w = (const float*)d_in[4];
    const float* conv_b = (const float*)d_in[5];
    const float* W_loc  = (const float*)d_in[6];
    const float* v_e    = (const float*)d_in[7];
    const float* pw1    = (const float*)d_in[8];
    const float* pb1    = (const float*)d_in[9];
    const float* pw2    = (const float*)d_in[10];
    const float* pb2    = (const float*)d_in[11];
    const float* Wi1    = (const float*)d_in[12];
    const float* Wh1    = (const float*)d_in[13];
    const float* bl1    = (const float*)d_in[14];
    const float* Wi2    = (const float*)d_in[15];
    const float* Wh2    = (const float*)d_in[16];
    const float* bl2    = (const float*)d_in[17];
    const float* Wp     = (const float*)d_in[18];
    const float* bp     = (const float*)d_in[19];
    float* out = (float*)d_out;
    (void)in_sizes; (void)n_in; (void)out_size; (void)ws_size;

    char* ws = (char*)d_ws;
    size_t off = 0;
    auto carve = [&](size_t bytes)->char* {
        char* p = ws + off;
        off += (bytes + 255) & ~(size_t)255;
        return p;
    };
    __half*    inputs_h = (__half*)   carve((size_t)BB*TENC*EE*2);
    __half*    pe_h     = (__half*)   carve((size_t)BB*TENC*AA*2);
    __half*    PIP      = (__half*)   carve((size_t)BB*TENC*NM*2);
    float*     XS1      = (float*)    carve((size_t)(TDEC+1)*BB*K1*4);
    _Float16*  W1T      = (_Float16*) carve((size_t)GG*K1*2);
    _Float16*  W2T      = (_Float16*) carve((size_t)GG*K2*2);
    _Float16*  WqT      = (_Float16*) carve((size_t)AA*HH*2);
    _Float16*  WohT     = (_Float16*) carve((size_t)NM*HH*2);
    // zeroed block: XS2 (2 parity) | c1 | c2 | awc
    const int NZ = 2*BB*K2 + HH*BB + HH*BB + BB*TENC;   // 131072+32768+32768+8192
    float* zblk = (float*)carve((size_t)NZ*4);
    float* XS2 = zblk;
    float* c1  = XS2 + 2*BB*K2;
    float* c2  = c1 + HH*BB;
    float* awc = c2 + HH*BB;
    float* e_ws = (float*)carve((size_t)BB*TENC*4);
    float* Mloc = (float*)carve((size_t)31*AA*4);
    float* cbp  = (float*)carve((size_t)AA*4);

    // ---- one-time precompute (per launch) ----
    k_zero<<<(NZ+255)/256,256,0,stream>>>(zblk, NZ);
    k_zero<<<(BB*K1+255)/256,256,0,stream>>>(XS1, BB*K1);   // row t=0 (prenet fills x part after)
    k_cvt_half<<<2048,256,0,stream>>>(inputs, inputs_h, BB*TENC*EE);
    k_proc_enc<<<BB*TENC,128,0,stream>>>(inputs, W_enc, pe_h);
    k_prenet<<<TDEC,256,0,stream>>>(pmels, pw1,pb1,pw2,pb2, XS1);
    k_mloc<<<1,128,0,stream>>>(conv_w, conv_b, W_loc, Mloc, cbp);
    k_transpose2<<<dim3(GG/32,  768/32),256,0,stream>>>(Wi1, W1T, 768,  GG, K1, 0,    1);
    k_transpose2<<<dim3(GG/32, 1024/32),256,0,stream>>>(Wh1, W1T, 1024, GG, K1, 768,  1);
    k_transpose2<<<dim3(GG/32, 1024/32),256,0,stream>>>(Wi2, W2T, 1024, GG, K2, 0,    1);
    k_transpose2<<<dim3(GG/32, 1024/32),256,0,stream>>>(Wh2, W2T, 1024, GG, K2, 1024, 1);
    k_transpose2<<<dim3(AA/32, 1024/32),256,0,stream>>>(W_q, WqT, 1024, AA, HH, 0,    0);
    k_transpose2<<<dim3(3,     1024/32),256,0,stream>>>(Wp,  WohT, 1024, NM, HH, 0,   0);
    k_pip<<<BB*64,320,0,stream>>>(inputs, Wp + (size_t)HH*NM, PIP);

    // ---- sequential decode: 4 kernels/step ----
    for(int t=0; t<TDEC; t++){
        const int p = t & 1;
        float* xs1cur  = XS1 + (size_t)t*BB*K1;
        float* xs1next = XS1 + (size_t)(t+1)*BB*K1;
        float* xs2p    = XS2 + (size_t)p*BB*K2;
        float* xs2n    = XS2 + (size_t)(1-p)*BB*K2;

        k_lstm<<<256,512,0,stream>>>(xs1cur, W1T, K1, bl1, c1,
                                     xs2p, K2, 0,          // h1 -> XS2[p][b][0:1024]
                                     xs1next, K1, 768);    // h1 -> next XS1 row
        k_lstm<<<256,512,0,stream>>>(xs2p, W2T, K2, bl2, c2,
                                     xs2n, K2, 1024,       // h2 -> XS2[1-p][b][1024:2048]
                                     (float*)nullptr, 0, 0);
        k_qe<<<256,256,0,stream>>>(xs2n, WqT, cbp, Mloc, v_e, awc, pe_h, e_ws);
        k_attn<<<BB,256,0,stream>>>(e_ws, inputs_h, PIP, awc, xs1next, xs2n,
                                    WohT, bp, out, t);
    }
}